// Round 3
// baseline (256.910 us; speedup 1.0000x reference)
//
#include <hip/hip_runtime.h>

#define NN 8192     // nodes
#define NB 32       // graphs
#define NG 256      // nodes per graph
#define NE 65536    // edges per graph type
#define DK 512
#define HC 32
#define DB 2048     // body visual dim
#define DF 512      // face visual dim

#define BODY_DW (NN*DB/4)            // 4194304 dwords of fp8x4 (body)
#define FACE_DW (NN*DF/4)            // 1048576 dwords of fp8x4 (face)
#define B_BODY (BODY_DW/2048)        // 2048 pack blocks (8 KB window = 4 body rows)
#define B_FACE (FACE_DW/2048)        // 512 pack blocks (8 KB window = 16 face rows)
#define WB_BODY (NE/64)              // 1024 scat blocks body (16 edges/wave, 4 waves)
#define WB_FACE (NE/64)              // 1024 scat blocks face

typedef float v2f __attribute__((ext_vector_type(2)));
typedef float v4f __attribute__((ext_vector_type(4)));

#if __has_builtin(__builtin_amdgcn_cvt_pk_f32_fp8) && __has_builtin(__builtin_amdgcn_cvt_pk_fp8_f32)
#define HW_FP8 1
#else
#define HW_FP8 0
#endif

#if __has_builtin(__builtin_amdgcn_mfma_f32_16x16x32_fp8_fp8)
#define HW_MFMA8 1
#else
#define HW_MFMA8 0
#endif

// ---- fp8 e4m3fn helpers (manual fallback only if builtins missing) ----
__device__ __forceinline__ float fp8_dec(unsigned u) {
    unsigned e = (u >> 3) & 15u, m = u & 7u, s = u & 0x80u;
    float v = e ? __uint_as_float(((e + 120u) << 23) | (m << 20))
                : (float)m * 0.001953125f;
    return s ? -v : v;
}
__device__ __forceinline__ unsigned fp8_enc(float x) {
    unsigned sb = (__float_as_uint(x) >> 24) & 0x80u;
    float a = fabsf(x);
    if (a >= 448.f) return sb | 0x7Eu;
    if (a < 0.015625f) {
        int c = (int)rintf(a * 512.f);
        if (c > 7) return sb | 0x08u;
        return sb | (unsigned)c;
    }
    int ex; (void)frexpf(a, &ex);
    float p = ldexpf(a, 1 - ex);
    int m = (int)rintf((p - 1.f) * 8.f);
    int e = ex - 1 + 7;
    if (m == 8) { m = 0; e++; }
    if (e >= 16) return sb | 0x7Eu;
    return sb | (unsigned)(e << 3) | (unsigned)m;
}
__device__ __forceinline__ unsigned pack4_fp8(float x, float y, float z, float w) {
#if HW_FP8
    int u = __builtin_amdgcn_cvt_pk_fp8_f32(x, y, 0, false);
    u = __builtin_amdgcn_cvt_pk_fp8_f32(z, w, u, true);
    return (unsigned)u;
#else
    return fp8_enc(x) | (fp8_enc(y) << 8) | (fp8_enc(z) << 16) | (fp8_enc(w) << 24);
#endif
}
__device__ __forceinline__ float fp8dot4(unsigned a, unsigned b) {
#if HW_FP8
    v2f al = __builtin_amdgcn_cvt_pk_f32_fp8((int)a, false);
    v2f ah = __builtin_amdgcn_cvt_pk_f32_fp8((int)a, true);
    v2f bl = __builtin_amdgcn_cvt_pk_f32_fp8((int)b, false);
    v2f bh = __builtin_amdgcn_cvt_pk_f32_fp8((int)b, true);
    return al.x*bl.x + al.y*bl.y + ah.x*bh.x + ah.y*bh.y;
#else
    float s = 0.f;
    #pragma unroll
    for (int j = 0; j < 4; j++)
        s += fp8_dec((a >> (8*j)) & 255u) * fp8_dec((b >> (8*j)) & 255u);
    return s;
#endif
}
__device__ __forceinline__ float d4(float4 v) {
    return v.x*v.x + v.y*v.y + v.z*v.z + v.w*v.w;
}

struct Params {
    const float *vb, *vf, *x, *Wq, *Wk, *Wv, *ln_g, *ln_b, *prelu_a;
    const float *mlp_W, *mlp_b, *np_W, *np_b, *body_W, *body_b, *face_W, *face_b;
    const float *pb_W, *pb_b, *pf_W, *pf_b;
    const int *eib, *eif;
    unsigned *vnb, *vnf;
    float *invb, *invf;
    float *a_ws, *sb, *sf, *fused;
    // fused[0..31]=body_W@pb_W, [32..63]=face_W@pf_W, [64]=cb, [65]=cf,
    // [66..70] = s0,s1,q00,q01,q11 (Wv column statistics)
    float *out;
};

// ===== K1: fp8 pack + fused fp32 invnorm + rank-2 attention + constant precompute =====
__global__ __launch_bounds__(256) void k1_kernel(Params p) {
    __shared__ float2 xs[NG];
    __shared__ float pm[4][4];
    __shared__ float sm4[4];
    __shared__ float rss[16];
    __shared__ float wred[4][8];
    const int bid = blockIdx.x, tid = threadIdx.x;
    const int lane = tid & 63, wave = tid >> 6;

    if (bid < B_BODY + B_FACE) {
        const bool body = bid < B_BODY;
        const float4* __restrict__ src = body ? (const float4*)p.vb : (const float4*)p.vf;
        unsigned* __restrict__ dst = body ? p.vnb : p.vnf;
        const int base = (body ? bid : bid - B_BODY) * 2048 + tid;
        if (tid < 16) rss[tid] = 0.f;
        __syncthreads();
        float4 v0 = src[base];
        float4 v1 = src[base + 256];
        float4 v2 = src[base + 512];
        float4 v3 = src[base + 768];
        float4 v4 = src[base + 1024];
        float4 v5 = src[base + 1280];
        float4 v6 = src[base + 1536];
        float4 v7 = src[base + 1792];
        __builtin_amdgcn_sched_barrier(0);   // hard fence: all 8 loads issue before any pack
        dst[base]        = pack4_fp8(v0.x, v0.y, v0.z, v0.w);
        dst[base + 256]  = pack4_fp8(v1.x, v1.y, v1.z, v1.w);
        dst[base + 512]  = pack4_fp8(v2.x, v2.y, v2.z, v2.w);
        dst[base + 768]  = pack4_fp8(v3.x, v3.y, v3.z, v3.w);
        dst[base + 1024] = pack4_fp8(v4.x, v4.y, v4.z, v4.w);
        dst[base + 1280] = pack4_fp8(v5.x, v5.y, v5.z, v5.w);
        dst[base + 1536] = pack4_fp8(v6.x, v6.y, v6.z, v6.w);
        dst[base + 1792] = pack4_fp8(v7.x, v7.y, v7.z, v7.w);
        if (body) {
            float sq[4];
            sq[0] = d4(v0) + d4(v1);
            sq[1] = d4(v2) + d4(v3);
            sq[2] = d4(v4) + d4(v5);
            sq[3] = d4(v6) + d4(v7);
            #pragma unroll
            for (int r = 0; r < 4; r++) {
                float ss = sq[r];
                #pragma unroll
                for (int off = 32; off > 0; off >>= 1) ss += __shfl_xor(ss, off);
                if (lane == 0) atomicAdd(&rss[r], ss);
            }
            __syncthreads();
            if (tid < 4) p.invb[bid*4 + tid] = rsqrtf(rss[tid] + 1e-8f);
        } else {
            float sq[8] = {d4(v0), d4(v1), d4(v2), d4(v3), d4(v4), d4(v5), d4(v6), d4(v7)};
            #pragma unroll
            for (int j = 0; j < 8; j++) {
                float ss = sq[j];
                #pragma unroll
                for (int off = 32; off > 0; off >>= 1) ss += __shfl_xor(ss, off);
                if (lane == 0) atomicAdd(&rss[(wave >> 1) + 2*j], ss);
            }
            __syncthreads();
            if (tid < 16) p.invf[(bid - B_BODY)*16 + tid] = rsqrtf(rss[tid] + 1e-8f);
        }
        return;
    }
    if (bid < B_BODY + B_FACE + NB) {
        const int gg = bid - (B_BODY + B_FACE);
        xs[tid] = ((const float2*)p.x)[gg*NG + tid];
        const int d = tid * 2;
        float q0a = p.Wq[d],    q0b = p.Wq[d+1];
        float q1a = p.Wq[DK+d], q1b = p.Wq[DK+d+1];
        float k0a = p.Wk[d],    k0b = p.Wk[d+1];
        float k1a = p.Wk[DK+d], k1b = p.Wk[DK+d+1];
        float m00 = q0a*k0a + q0b*k0b;
        float m01 = q0a*k1a + q0b*k1b;
        float m10 = q1a*k0a + q1b*k0b;
        float m11 = q1a*k1a + q1b*k1b;
        #pragma unroll
        for (int off = 32; off > 0; off >>= 1) {
            m00 += __shfl_down(m00,off); m01 += __shfl_down(m01,off);
            m10 += __shfl_down(m10,off); m11 += __shfl_down(m11,off);
        }
        if (lane == 0) { pm[wave][0]=m00; pm[wave][1]=m01; pm[wave][2]=m10; pm[wave][3]=m11; }
        __syncthreads();
        if (tid < 4) sm4[tid] = pm[0][tid] + pm[1][tid] + pm[2][tid] + pm[3][tid];
        __syncthreads();
        const float scale = 0.04419417382415922f;  // 1/sqrt(512)
        const float2 xi = xs[tid];
        const float u0 = (xi.x*sm4[0] + xi.y*sm4[2]) * scale;
        const float u1 = (xi.x*sm4[1] + xi.y*sm4[3]) * scale;
        float m = -1e30f;
        for (int j = 0; j < NG; j++) m = fmaxf(m, u0*xs[j].x + u1*xs[j].y);
        float S = 0.f, a0 = 0.f, a1 = 0.f;
        for (int j = 0; j < NG; j++) {
            float2 xj = xs[j];
            float pr = __expf(u0*xj.x + u1*xj.y - m);
            S += pr; a0 += pr*xj.x; a1 += pr*xj.y;
        }
        const float invS = 1.f / S;
        ((float2*)p.a_ws)[gg*NG + tid] = make_float2(a0*invS, a1*invS);
        return;
    }
    // ---- tail block: Wv stats + fused projection vectors ----
    {
        const int d = tid * 2;
        float u0 = p.Wv[d], u1 = p.Wv[d+1];
        float w0 = p.Wv[DK+d], w1 = p.Wv[DK+d+1];
        float s0 = u0 + u1, s1 = w0 + w1;
        float q00 = u0*u0 + u1*u1, q01 = u0*w0 + u1*w1, q11 = w0*w0 + w1*w1;
        #pragma unroll
        for (int off = 1; off < 64; off <<= 1) {
            s0 += __shfl_xor(s0,off); s1 += __shfl_xor(s1,off);
            q00 += __shfl_xor(q00,off); q01 += __shfl_xor(q01,off); q11 += __shfl_xor(q11,off);
        }
        if (lane == 0) {
            wred[wave][0]=s0; wred[wave][1]=s1; wred[wave][2]=q00; wred[wave][3]=q01; wred[wave][4]=q11;
        }
        __syncthreads();
        if (tid < 5) p.fused[66+tid] = wred[0][tid]+wred[1][tid]+wred[2][tid]+wred[3][tid];
    }
    if (tid < HC) {
        float s = 0.f;
        #pragma unroll 8
        for (int c = 0; c < HC; c++) s += p.body_W[tid*HC + c] * p.pb_W[c];
        p.fused[tid] = s;
    } else if (tid < 2*HC) {
        const int cp = tid - HC;
        float s = 0.f;
        #pragma unroll 8
        for (int c = 0; c < HC; c++) s += p.face_W[cp*HC + c] * p.pf_W[c];
        p.fused[HC + cp] = s;
    } else if (tid == 2*HC) {
        float s = 0.f;
        for (int c = 0; c < HC; c++) s += p.body_b[c] * p.pb_W[c];
        p.fused[64] = s;
    } else if (tid == 2*HC + 1) {
        float s = 0.f;
        for (int c = 0; c < HC; c++) s += p.face_b[c] * p.pf_W[c];
        p.fused[65] = s;
    }
}

// ===== K2: node MLP pipeline -> out base + sb/sf scalars (1 node / wave) =====
__global__ __launch_bounds__(256) void k2_kernel(Params p) {
    __shared__ __align__(16) float t[4][DK];
    const int tid = threadIdx.x;
    const int wave = tid >> 6, lane = tid & 63;
    const int node = blockIdx.x * 4 + wave;

    const float a0 = p.a_ws[node*2], a1 = p.a_ws[node*2+1];
    const float s0 = p.fused[66], s1 = p.fused[67];
    const float q00 = p.fused[68], q01 = p.fused[69], q11 = p.fused[70];
    const float mean = (a0*s0 + a1*s1) * (1.f/DK);
    const float msq  = (a0*a0*q00 + 2.f*a0*a1*q01 + a1*a1*q11) * (1.f/DK);
    const float inv  = rsqrtf(msq - mean*mean + 1e-5f);
    const float alpha = p.prelu_a[0];

    const v4f* wv0 = (const v4f*)p.Wv;
    const v4f* wv1 = (const v4f*)(p.Wv + DK);
    const v4f* g4 = (const v4f*)p.ln_g;
    const v4f* b4 = (const v4f*)p.ln_b;
    #pragma unroll
    for (int k = 0; k < 2; k++) {
        const int c4 = lane*2 + k;
        v4f od = a0*wv0[c4] + a1*wv1[c4];
        v4f nd = (od - mean) * inv * g4[c4] + b4[c4];
        v4f pr;
        pr.x = (nd.x >= 0.f) ? nd.x : alpha*nd.x;
        pr.y = (nd.y >= 0.f) ? nd.y : alpha*nd.y;
        pr.z = (nd.z >= 0.f) ? nd.z : alpha*nd.z;
        pr.w = (nd.w >= 0.f) ? nd.w : alpha*nd.w;
        *(v4f*)&t[wave][c4*4] = pr;
    }
    __syncthreads();

    // GEMV h = t @ mlp_W : lane = (dg = lane>>3, c8 = lane&7); float4 W loads
    const int dg = lane >> 3, c8 = lane & 7;
    const v4f* W4 = (const v4f*)p.mlp_W;   // [512][8] float4
    const float* tw = t[wave] + dg*64;
    v4f h4 = {0.f, 0.f, 0.f, 0.f};
    #pragma unroll 4
    for (int j = 0; j < 16; j++) {
        const int dd = ((j + dg*2) & 15) * 4;       // rotate start per dg: avoid LDS bank pileup
        v4f t4 = *(const v4f*)(tw + dd);
        const int d = dg*64 + dd;
        h4 += t4.x * W4[(d+0)*8 + c8]
            + t4.y * W4[(d+1)*8 + c8]
            + t4.z * W4[(d+2)*8 + c8]
            + t4.w * W4[(d+3)*8 + c8];
    }
    #pragma unroll
    for (int off = 8; off < 64; off <<= 1) {
        h4.x += __shfl_xor(h4.x, off);
        h4.y += __shfl_xor(h4.y, off);
        h4.z += __shfl_xor(h4.z, off);
        h4.w += __shfl_xor(h4.w, off);
    }
    h4 += ((const v4f*)p.mlp_b)[c8];
    v4f n4 = ((const v4f*)p.np_W)[c8];
    v4f f4b = ((const v4f*)p.fused)[c8];
    v4f f4f = ((const v4f*)(p.fused + HC))[c8];
    float v0 = h4.x*n4.x + h4.y*n4.y + h4.z*n4.z + h4.w*n4.w;
    float v1 = h4.x*f4b.x + h4.y*f4b.y + h4.z*f4b.z + h4.w*f4b.w;
    float v2 = h4.x*f4f.x + h4.y*f4f.y + h4.z*f4f.z + h4.w*f4f.w;
    #pragma unroll
    for (int off = 1; off < 8; off <<= 1) {
        v0 += __shfl_xor(v0, off);
        v1 += __shfl_xor(v1, off);
        v2 += __shfl_xor(v2, off);
    }
    if (lane == 0) {
        p.out[node] = v0 + p.np_b[0] + p.pb_b[0] + p.pf_b[0];   // base; edges atomically add
        p.sb[node] = v1 + p.fused[64];
        p.sf[node] = v2 + p.fused[65];
    }
}

// ===== K3: edge cosine scatter via MFMA diagonal (16 edges / wave) =====
// lane l: feeds A with src_row[l&15], B with dst_row[l&15], k-chunk (l>>4)*8.
// D[e][e] = dot(src_e, dst_e); diagonal positions: col(lane&15) == row((lane>>4)*4+r).
__global__ __launch_bounds__(256) void scat_kernel(Params p) {
    const int wave = threadIdx.x >> 6, lane = threadIdx.x & 63;
    const int er = lane & 15;
    const int kb = (lane >> 4) * 8;
    if (blockIdx.x < WB_BODY) {
        const int e0 = (blockIdx.x * 4 + wave) * 16;
        const int s = p.eib[e0 + er];
        const int d = p.eib[NE + e0 + er];
        const char* __restrict__ A  = (const char*)p.vnb + (size_t)s * DB + kb;
        const char* __restrict__ Bq = (const char*)p.vnb + (size_t)d * DB + kb;
        const float scale = p.invb[s] * p.invb[d] * p.sb[s];
#if HW_MFMA8
        v4f acc0 = {0.f,0.f,0.f,0.f}, acc1 = {0.f,0.f,0.f,0.f};
        #pragma unroll 4
        for (int k = 0; k < DB; k += 64) {
            long long a0 = *(const long long*)(A + k);
            long long b0 = *(const long long*)(Bq + k);
            long long a1 = *(const long long*)(A + k + 32);
            long long b1 = *(const long long*)(Bq + k + 32);
            acc0 = __builtin_amdgcn_mfma_f32_16x16x32_fp8_fp8(a0, b0, acc0, 0, 0, 0);
            acc1 = __builtin_amdgcn_mfma_f32_16x16x32_fp8_fp8(a1, b1, acc1, 0, 0, 0);
        }
        v4f acc = acc0 + acc1;
        const int row0 = (lane >> 4) * 4;
        #pragma unroll
        for (int r = 0; r < 4; r++)
            if (row0 + r == er) atomicAdd(&p.out[d], acc[r] * scale);
#else
        float part = 0.f;
        #pragma unroll 4
        for (int k = 0; k < DB; k += 32) {
            int2 a = *(const int2*)(A + k);
            int2 b = *(const int2*)(Bq + k);
            part += fp8dot4((unsigned)a.x,(unsigned)b.x) + fp8dot4((unsigned)a.y,(unsigned)b.y);
        }
        part += __shfl_xor(part, 16);
        part += __shfl_xor(part, 32);
        if (lane < 16) atomicAdd(&p.out[d], part * scale);
#endif
    } else {
        const int e0 = ((blockIdx.x - WB_BODY) * 4 + wave) * 16;
        const int s = p.eif[e0 + er];
        const int d = p.eif[NE + e0 + er];
        const char* __restrict__ A  = (const char*)p.vnf + (size_t)s * DF + kb;
        const char* __restrict__ Bq = (const char*)p.vnf + (size_t)d * DF + kb;
        const float scale = p.invf[s] * p.invf[d] * p.sf[s];
#if HW_MFMA8
        v4f acc0 = {0.f,0.f,0.f,0.f}, acc1 = {0.f,0.f,0.f,0.f};
        #pragma unroll 4
        for (int k = 0; k < DF; k += 64) {
            long long a0 = *(const long long*)(A + k);
            long long b0 = *(const long long*)(Bq + k);
            long long a1 = *(const long long*)(A + k + 32);
            long long b1 = *(const long long*)(Bq + k + 32);
            acc0 = __builtin_amdgcn_mfma_f32_16x16x32_fp8_fp8(a0, b0, acc0, 0, 0, 0);
            acc1 = __builtin_amdgcn_mfma_f32_16x16x32_fp8_fp8(a1, b1, acc1, 0, 0, 0);
        }
        v4f acc = acc0 + acc1;
        const int row0 = (lane >> 4) * 4;
        #pragma unroll
        for (int r = 0; r < 4; r++)
            if (row0 + r == er) atomicAdd(&p.out[d], acc[r] * scale);
#else
        float part = 0.f;
        #pragma unroll 4
        for (int k = 0; k < DF; k += 32) {
            int2 a = *(const int2*)(A + k);
            int2 b = *(const int2*)(Bq + k);
            part += fp8dot4((unsigned)a.x,(unsigned)b.x) + fp8dot4((unsigned)a.y,(unsigned)b.y);
        }
        part += __shfl_xor(part, 16);
        part += __shfl_xor(part, 32);
        if (lane < 16) atomicAdd(&p.out[d], part * scale);
#endif
    }
}

extern "C" void kernel_launch(void* const* d_in, const int* in_sizes, int n_in,
                              void* d_out, int out_size, void* d_ws, size_t ws_size,
                              hipStream_t stream) {
    char* ws = (char*)d_ws;
    size_t off = 0;
    auto alloc = [&](size_t bytes) { void* pp = ws + off; off += (bytes + 15) & ~size_t(15); return pp; };

    Params p;
    p.vb      = (const float*)d_in[1];
    p.vf      = (const float*)d_in[2];
    p.x       = (const float*)d_in[0];
    p.Wq      = (const float*)d_in[3];
    p.Wk      = (const float*)d_in[4];
    p.Wv      = (const float*)d_in[5];
    p.ln_g    = (const float*)d_in[6];
    p.ln_b    = (const float*)d_in[7];
    p.prelu_a = (const float*)d_in[8];
    p.mlp_W   = (const float*)d_in[9];
    p.mlp_b   = (const float*)d_in[10];
    p.np_W    = (const float*)d_in[11];
    p.np_b    = (const float*)d_in[12];
    p.body_W  = (const float*)d_in[13];
    p.body_b  = (const float*)d_in[14];
    p.face_W  = (const float*)d_in[15];
    p.face_b  = (const float*)d_in[16];
    p.pb_W    = (const float*)d_in[17];
    p.pb_b    = (const float*)d_in[18];
    p.pf_W    = (const float*)d_in[19];
    p.pf_b    = (const float*)d_in[20];
    p.eib     = (const int*)d_in[21];
    p.eif     = (const int*)d_in[22];
    p.vnb     = (unsigned*)alloc((size_t)BODY_DW*4);     // 16 MB fp8
    p.vnf     = (unsigned*)alloc((size_t)FACE_DW*4);     //  4 MB fp8
    p.invb    = (float*)alloc((size_t)NN*4);
    p.invf    = (float*)alloc((size_t)NN*4);
    p.a_ws    = (float*)alloc((size_t)NN*2*4);
    p.sb      = (float*)alloc((size_t)NN*4);
    p.sf      = (float*)alloc((size_t)NN*4);
    p.fused   = (float*)alloc((size_t)72*4);
    p.out     = (float*)d_out;

    k1_kernel<<<B_BODY + B_FACE + NB + 1, 256, 0, stream>>>(p);
    k2_kernel<<<NN/4, 256, 0, stream>>>(p);
    scat_kernel<<<WB_BODY + WB_FACE, 256, 0, stream>>>(p);
}

// Round 4
// 197.739 us; speedup vs baseline: 1.2992x; 1.2992x over previous
//
#include <hip/hip_runtime.h>

#define NN 8192     // nodes
#define NB 32       // graphs
#define NG 256      // nodes per graph
#define NE 65536    // edges per graph type
#define DK 512
#define HC 32
#define DB 2048     // body visual dim
#define DF 512      // face visual dim

#define BODY_DW (NN*DB/4)            // 4194304 dwords of int8x4 (body)
#define FACE_DW (NN*DF/4)            // 1048576 dwords of int8x4 (face)
#define B_BODY (BODY_DW/2048)        // 2048 pack blocks (8 KB window = 4 body rows)
#define B_FACE (FACE_DW/2048)        // 512 pack blocks (8 KB window = 16 face rows)
#define QSCALE 16.0f                 // int8 quant scale; 1/S^2 folded into sb/sf

typedef float v4f __attribute__((ext_vector_type(4)));

#if __has_builtin(__builtin_amdgcn_sdot4)
#define HW_SDOT 1
#else
#define HW_SDOT 0
#endif

__device__ __forceinline__ unsigned pack4_i8(float4 v) {
    int i0 = (int)rintf(fmaxf(fminf(v.x * QSCALE, 127.f), -127.f));
    int i1 = (int)rintf(fmaxf(fminf(v.y * QSCALE, 127.f), -127.f));
    int i2 = (int)rintf(fmaxf(fminf(v.z * QSCALE, 127.f), -127.f));
    int i3 = (int)rintf(fmaxf(fminf(v.w * QSCALE, 127.f), -127.f));
    return (unsigned)(i0 & 255) | ((unsigned)(i1 & 255) << 8)
         | ((unsigned)(i2 & 255) << 16) | ((unsigned)(i3 & 255) << 24);
}
__device__ __forceinline__ int sdot4(int a, int b, int c) {
#if HW_SDOT
    return __builtin_amdgcn_sdot4(a, b, c, false);
#else
    c += (int)(signed char)(a)       * (int)(signed char)(b);
    c += (int)(signed char)(a >> 8)  * (int)(signed char)(b >> 8);
    c += (int)(signed char)(a >> 16) * (int)(signed char)(b >> 16);
    c += (int)(signed char)(a >> 24) * (int)(signed char)(b >> 24);
    return c;
#endif
}
__device__ __forceinline__ int dot16(int4 a, int4 b, int c) {
    c = sdot4(a.x, b.x, c);
    c = sdot4(a.y, b.y, c);
    c = sdot4(a.z, b.z, c);
    c = sdot4(a.w, b.w, c);
    return c;
}
__device__ __forceinline__ float d4(float4 v) {
    return v.x*v.x + v.y*v.y + v.z*v.z + v.w*v.w;
}
__device__ __forceinline__ v4f prelu4(v4f nd, float alpha) {
    v4f r;
    r.x = (nd.x >= 0.f) ? nd.x : alpha*nd.x;
    r.y = (nd.y >= 0.f) ? nd.y : alpha*nd.y;
    r.z = (nd.z >= 0.f) ? nd.z : alpha*nd.z;
    r.w = (nd.w >= 0.f) ? nd.w : alpha*nd.w;
    return r;
}

struct Params {
    const float *vb, *vf, *x, *Wq, *Wk, *Wv, *ln_g, *ln_b, *prelu_a;
    const float *mlp_W, *mlp_b, *np_W, *np_b, *body_W, *body_b, *face_W, *face_b;
    const float *pb_W, *pb_b, *pf_W, *pf_b;
    const int *eib, *eif;
    unsigned *vnb, *vnf;          // int8x4 tables
    float *invb, *invf;
    float *a_ws, *sb, *sf, *fused;
    // fused[64]=cb (body_b.pb_W), [65]=cf, [66..70]=s0,s1,q00,q01,q11 (Wv col stats)
    float *mvec;                  // [0,512)=mlp_W@np_W, [512,1024)=mlp_W@fb, [1024,1536)=mlp_W@ff,
                                  // [1536..1538]=mlp_b.{np,fb,ff}
    float *out;
};

// ===== K1: attention (first) + precompute tail + int8 pack with fused fp32 invnorm =====
// blocks [0, NB)        : rank-2 attention (serial loops — start them first)
// block  NB             : Wv stats + fused vecs + mvec precompute
// blocks [NB+1, ...)    : pack body then face
__global__ __launch_bounds__(256) void k1_kernel(Params p) {
    __shared__ float2 xs[NG];
    __shared__ float pm[4][4];
    __shared__ float sm4[4];
    __shared__ float rss[16];
    __shared__ float wred[4][8];
    __shared__ float fs_np[HC], fs_fb[HC], fs_ff[HC];
    const int bid = blockIdx.x, tid = threadIdx.x;
    const int lane = tid & 63, wave = tid >> 6;

    if (bid < NB) {
        const int gg = bid;
        xs[tid] = ((const float2*)p.x)[gg*NG + tid];
        const int d = tid * 2;
        float q0a = p.Wq[d],    q0b = p.Wq[d+1];
        float q1a = p.Wq[DK+d], q1b = p.Wq[DK+d+1];
        float k0a = p.Wk[d],    k0b = p.Wk[d+1];
        float k1a = p.Wk[DK+d], k1b = p.Wk[DK+d+1];
        float m00 = q0a*k0a + q0b*k0b;
        float m01 = q0a*k1a + q0b*k1b;
        float m10 = q1a*k0a + q1b*k0b;
        float m11 = q1a*k1a + q1b*k1b;
        #pragma unroll
        for (int off = 32; off > 0; off >>= 1) {
            m00 += __shfl_down(m00,off); m01 += __shfl_down(m01,off);
            m10 += __shfl_down(m10,off); m11 += __shfl_down(m11,off);
        }
        if (lane == 0) { pm[wave][0]=m00; pm[wave][1]=m01; pm[wave][2]=m10; pm[wave][3]=m11; }
        __syncthreads();
        if (tid < 4) sm4[tid] = pm[0][tid] + pm[1][tid] + pm[2][tid] + pm[3][tid];
        __syncthreads();
        const float scale = 0.04419417382415922f;  // 1/sqrt(512)
        const float2 xi = xs[tid];
        const float u0 = (xi.x*sm4[0] + xi.y*sm4[2]) * scale;
        const float u1 = (xi.x*sm4[1] + xi.y*sm4[3]) * scale;
        float m = -1e30f;
        for (int j = 0; j < NG; j++) m = fmaxf(m, u0*xs[j].x + u1*xs[j].y);
        float S = 0.f, a0 = 0.f, a1 = 0.f;
        for (int j = 0; j < NG; j++) {
            float2 xj = xs[j];
            float pr = __expf(u0*xj.x + u1*xj.y - m);
            S += pr; a0 += pr*xj.x; a1 += pr*xj.y;
        }
        const float invS = 1.f / S;
        ((float2*)p.a_ws)[gg*NG + tid] = make_float2(a0*invS, a1*invS);
        return;
    }
    if (bid == NB) {
        // Wv column statistics
        {
            const int d = tid * 2;
            float u0 = p.Wv[d], u1 = p.Wv[d+1];
            float w0 = p.Wv[DK+d], w1 = p.Wv[DK+d+1];
            float s0 = u0 + u1, s1 = w0 + w1;
            float q00 = u0*u0 + u1*u1, q01 = u0*w0 + u1*w1, q11 = w0*w0 + w1*w1;
            #pragma unroll
            for (int off = 1; off < 64; off <<= 1) {
                s0 += __shfl_xor(s0,off); s1 += __shfl_xor(s1,off);
                q00 += __shfl_xor(q00,off); q01 += __shfl_xor(q01,off); q11 += __shfl_xor(q11,off);
            }
            if (lane == 0) {
                wred[wave][0]=s0; wred[wave][1]=s1; wred[wave][2]=q00; wred[wave][3]=q01; wred[wave][4]=q11;
            }
        }
        // fused projection vectors into LDS
        if (tid < HC) {
            float sB = 0.f, sF = 0.f;
            #pragma unroll 8
            for (int c = 0; c < HC; c++) {
                sB += p.body_W[tid*HC + c] * p.pb_W[c];
                sF += p.face_W[tid*HC + c] * p.pf_W[c];
            }
            fs_fb[tid] = sB; fs_ff[tid] = sF;
            fs_np[tid] = p.np_W[tid];
        } else if (tid == HC) {
            float s = 0.f;
            for (int c = 0; c < HC; c++) s += p.body_b[c] * p.pb_W[c];
            p.fused[64] = s;
        } else if (tid == HC + 1) {
            float s = 0.f;
            for (int c = 0; c < HC; c++) s += p.face_b[c] * p.pf_W[c];
            p.fused[65] = s;
        }
        __syncthreads();
        if (tid < 5) p.fused[66+tid] = wred[0][tid]+wred[1][tid]+wred[2][tid]+wred[3][tid];
        // collapse mlp_W against the three projection vectors
        #pragma unroll
        for (int rr = tid; rr < DK; rr += 256) {
            const float* row = p.mlp_W + rr*HC;
            float dnp = 0.f, db = 0.f, df = 0.f;
            #pragma unroll 8
            for (int c = 0; c < HC; c++) {
                float w = row[c];
                dnp += w * fs_np[c]; db += w * fs_fb[c]; df += w * fs_ff[c];
            }
            p.mvec[rr] = dnp; p.mvec[DK + rr] = db; p.mvec[2*DK + rr] = df;
        }
        if (tid < 3) {
            const float* fv = (tid == 0) ? fs_np : (tid == 1) ? fs_fb : fs_ff;
            float s = 0.f;
            for (int c = 0; c < HC; c++) s += p.mlp_b[c] * fv[c];
            p.mvec[3*DK + tid] = s;
        }
        return;
    }
    {
        const int pb = bid - (NB + 1);
        const bool body = pb < B_BODY;
        const float4* __restrict__ src = body ? (const float4*)p.vb : (const float4*)p.vf;
        unsigned* __restrict__ dst = body ? p.vnb : p.vnf;
        const int base = (body ? pb : pb - B_BODY) * 2048 + tid;
        if (tid < 16) rss[tid] = 0.f;
        __syncthreads();
        float4 v0 = src[base];
        float4 v1 = src[base + 256];
        float4 v2 = src[base + 512];
        float4 v3 = src[base + 768];
        float4 v4 = src[base + 1024];
        float4 v5 = src[base + 1280];
        float4 v6 = src[base + 1536];
        float4 v7 = src[base + 1792];
        __builtin_amdgcn_sched_barrier(0);   // all 8 loads issue before any consumer
        dst[base]        = pack4_i8(v0);
        dst[base + 256]  = pack4_i8(v1);
        dst[base + 512]  = pack4_i8(v2);
        dst[base + 768]  = pack4_i8(v3);
        dst[base + 1024] = pack4_i8(v4);
        dst[base + 1280] = pack4_i8(v5);
        dst[base + 1536] = pack4_i8(v6);
        dst[base + 1792] = pack4_i8(v7);
        if (body) {
            float sq[4];
            sq[0] = d4(v0) + d4(v1);
            sq[1] = d4(v2) + d4(v3);
            sq[2] = d4(v4) + d4(v5);
            sq[3] = d4(v6) + d4(v7);
            #pragma unroll
            for (int r = 0; r < 4; r++) {
                float ss = sq[r];
                #pragma unroll
                for (int off = 32; off > 0; off >>= 1) ss += __shfl_xor(ss, off);
                if (lane == 0) atomicAdd(&rss[r], ss);
            }
            __syncthreads();
            if (tid < 4) p.invb[pb*4 + tid] = rsqrtf(rss[tid] + 1e-8f);
        } else {
            float sq[8] = {d4(v0), d4(v1), d4(v2), d4(v3), d4(v4), d4(v5), d4(v6), d4(v7)};
            #pragma unroll
            for (int j = 0; j < 8; j++) {
                float ss = sq[j];
                #pragma unroll
                for (int off = 32; off > 0; off >>= 1) ss += __shfl_xor(ss, off);
                if (lane == 0) atomicAdd(&rss[(wave >> 1) + 2*j], ss);
            }
            __syncthreads();
            if (tid < 16) p.invf[(pb - B_BODY)*16 + tid] = rsqrtf(rss[tid] + 1e-8f);
        }
    }
}

// ===== K2: node pipeline via collapsed projections (1 node / wave, no LDS) =====
__global__ __launch_bounds__(256) void k2_kernel(Params p) {
    const int tid = threadIdx.x;
    const int wave = tid >> 6, lane = tid & 63;
    const int node = blockIdx.x * 4 + wave;

    const float a0 = p.a_ws[node*2], a1 = p.a_ws[node*2+1];
    const float s0 = p.fused[66], s1 = p.fused[67];
    const float q00 = p.fused[68], q01 = p.fused[69], q11 = p.fused[70];
    const float mean = (a0*s0 + a1*s1) * (1.f/DK);
    const float msq  = (a0*a0*q00 + 2.f*a0*a1*q01 + a1*a1*q11) * (1.f/DK);
    const float inv  = rsqrtf(msq - mean*mean + 1e-5f);
    const float alpha = p.prelu_a[0];

    const v4f* wv0 = (const v4f*)p.Wv;
    const v4f* wv1 = (const v4f*)(p.Wv + DK);
    const v4f* g4 = (const v4f*)p.ln_g;
    const v4f* b4 = (const v4f*)p.ln_b;
    const v4f* mnp = (const v4f*)p.mvec;
    const v4f* mb  = (const v4f*)(p.mvec + DK);
    const v4f* mf  = (const v4f*)(p.mvec + 2*DK);

    const int c4 = lane * 2;
    v4f t0 = prelu4((a0*wv0[c4]   + a1*wv1[c4]   - mean) * inv * g4[c4]   + b4[c4],   alpha);
    v4f t1 = prelu4((a0*wv0[c4+1] + a1*wv1[c4+1] - mean) * inv * g4[c4+1] + b4[c4+1], alpha);

    v4f q0 = t0*mnp[c4] + t1*mnp[c4+1];
    v4f q1 = t0*mb[c4]  + t1*mb[c4+1];
    v4f q2 = t0*mf[c4]  + t1*mf[c4+1];
    float d0 = (q0.x+q0.y) + (q0.z+q0.w);
    float d1 = (q1.x+q1.y) + (q1.z+q1.w);
    float d2 = (q2.x+q2.y) + (q2.z+q2.w);
    #pragma unroll
    for (int off = 1; off < 64; off <<= 1) {
        d0 += __shfl_xor(d0, off);
        d1 += __shfl_xor(d1, off);
        d2 += __shfl_xor(d2, off);
    }
    if (lane == 0) {
        const float qinv2 = 1.0f / (QSCALE * QSCALE);
        p.out[node] = d0 + p.mvec[3*DK] + p.np_b[0] + p.pb_b[0] + p.pf_b[0];
        p.sb[node] = (d1 + p.mvec[3*DK+1] + p.fused[64]) * qinv2;
        p.sf[node] = (d2 + p.mvec[3*DK+2] + p.fused[65]) * qinv2;
    }
}

// ===== K3: edge-direct int8 cosine scatter =====
// blocks [0, NE/8)         : body, 2 edges/wave (int4 row loads)
// blocks [NE/8, +NE/16)    : face, 4 edges/wave (int2 row loads)
__global__ __launch_bounds__(256) void scat_kernel(Params p) {
    const int wave = threadIdx.x >> 6, lane = threadIdx.x & 63;
    if (blockIdx.x < NE/8) {
        const int e = blockIdx.x * 8 + wave * 2;
        const int sA = p.eib[e],     dA = p.eib[NE + e];
        const int sB = p.eib[e + 1], dB = p.eib[NE + e + 1];
        const int4* A0 = (const int4*)(p.vnb + (size_t)sA * (DB/4));
        const int4* B0 = (const int4*)(p.vnb + (size_t)dA * (DB/4));
        const int4* A1 = (const int4*)(p.vnb + (size_t)sB * (DB/4));
        const int4* B1 = (const int4*)(p.vnb + (size_t)dB * (DB/4));
        int4 a00 = A0[lane], a01 = A0[lane + 64];
        int4 b00 = B0[lane], b01 = B0[lane + 64];
        int4 a10 = A1[lane], a11 = A1[lane + 64];
        int4 b10 = B1[lane], b11 = B1[lane + 64];
        int x0 = dot16(a01, b01, dot16(a00, b00, 0));
        int x1 = dot16(a11, b11, dot16(a10, b10, 0));
        #pragma unroll
        for (int off = 1; off < 64; off <<= 1) {
            x0 += __shfl_xor(x0, off);
            x1 += __shfl_xor(x1, off);
        }
        if (lane == 0) {
            atomicAdd(&p.out[dA], (float)x0 * p.invb[sA] * p.invb[dA] * p.sb[sA]);
            atomicAdd(&p.out[dB], (float)x1 * p.invb[sB] * p.invb[dB] * p.sb[sB]);
        }
    } else {
        const int e = (blockIdx.x - NE/8) * 16 + wave * 4;
        const int s0 = p.eif[e],     d0 = p.eif[NE + e];
        const int s1 = p.eif[e + 1], d1 = p.eif[NE + e + 1];
        const int s2 = p.eif[e + 2], d2 = p.eif[NE + e + 2];
        const int s3 = p.eif[e + 3], d3 = p.eif[NE + e + 3];
        const int2* ap0 = (const int2*)(p.vnf + (size_t)s0 * (DF/4));
        const int2* bp0 = (const int2*)(p.vnf + (size_t)d0 * (DF/4));
        const int2* ap1 = (const int2*)(p.vnf + (size_t)s1 * (DF/4));
        const int2* bp1 = (const int2*)(p.vnf + (size_t)d1 * (DF/4));
        const int2* ap2 = (const int2*)(p.vnf + (size_t)s2 * (DF/4));
        const int2* bp2 = (const int2*)(p.vnf + (size_t)d2 * (DF/4));
        const int2* ap3 = (const int2*)(p.vnf + (size_t)s3 * (DF/4));
        const int2* bp3 = (const int2*)(p.vnf + (size_t)d3 * (DF/4));
        int2 a0 = ap0[lane], b0 = bp0[lane];
        int2 a1 = ap1[lane], b1 = bp1[lane];
        int2 a2 = ap2[lane], b2 = bp2[lane];
        int2 a3 = ap3[lane], b3 = bp3[lane];
        int x0 = sdot4(a0.y, b0.y, sdot4(a0.x, b0.x, 0));
        int x1 = sdot4(a1.y, b1.y, sdot4(a1.x, b1.x, 0));
        int x2 = sdot4(a2.y, b2.y, sdot4(a2.x, b2.x, 0));
        int x3 = sdot4(a3.y, b3.y, sdot4(a3.x, b3.x, 0));
        #pragma unroll
        for (int off = 1; off < 64; off <<= 1) {
            x0 += __shfl_xor(x0, off);
            x1 += __shfl_xor(x1, off);
            x2 += __shfl_xor(x2, off);
            x3 += __shfl_xor(x3, off);
        }
        if (lane == 0) {
            atomicAdd(&p.out[d0], (float)x0 * p.invf[s0] * p.invf[d0] * p.sf[s0]);
            atomicAdd(&p.out[d1], (float)x1 * p.invf[s1] * p.invf[d1] * p.sf[s1]);
            atomicAdd(&p.out[d2], (float)x2 * p.invf[s2] * p.invf[d2] * p.sf[s2]);
            atomicAdd(&p.out[d3], (float)x3 * p.invf[s3] * p.invf[d3] * p.sf[s3]);
        }
    }
}

extern "C" void kernel_launch(void* const* d_in, const int* in_sizes, int n_in,
                              void* d_out, int out_size, void* d_ws, size_t ws_size,
                              hipStream_t stream) {
    char* ws = (char*)d_ws;
    size_t off = 0;
    auto alloc = [&](size_t bytes) { void* pp = ws + off; off += (bytes + 15) & ~size_t(15); return pp; };

    Params p;
    p.vb      = (const float*)d_in[1];
    p.vf      = (const float*)d_in[2];
    p.x       = (const float*)d_in[0];
    p.Wq      = (const float*)d_in[3];
    p.Wk      = (const float*)d_in[4];
    p.Wv      = (const float*)d_in[5];
    p.ln_g    = (const float*)d_in[6];
    p.ln_b    = (const float*)d_in[7];
    p.prelu_a = (const float*)d_in[8];
    p.mlp_W   = (const float*)d_in[9];
    p.mlp_b   = (const float*)d_in[10];
    p.np_W    = (const float*)d_in[11];
    p.np_b    = (const float*)d_in[12];
    p.body_W  = (const float*)d_in[13];
    p.body_b  = (const float*)d_in[14];
    p.face_W  = (const float*)d_in[15];
    p.face_b  = (const float*)d_in[16];
    p.pb_W    = (const float*)d_in[17];
    p.pb_b    = (const float*)d_in[18];
    p.pf_W    = (const float*)d_in[19];
    p.pf_b    = (const float*)d_in[20];
    p.eib     = (const int*)d_in[21];
    p.eif     = (const int*)d_in[22];
    p.vnb     = (unsigned*)alloc((size_t)BODY_DW*4);     // 16 MB int8
    p.vnf     = (unsigned*)alloc((size_t)FACE_DW*4);     //  4 MB int8
    p.invb    = (float*)alloc((size_t)NN*4);
    p.invf    = (float*)alloc((size_t)NN*4);
    p.a_ws    = (float*)alloc((size_t)NN*2*4);
    p.sb      = (float*)alloc((size_t)NN*4);
    p.sf      = (float*)alloc((size_t)NN*4);
    p.fused   = (float*)alloc((size_t)72*4);
    p.mvec    = (float*)alloc((size_t)1544*4);
    p.out     = (float*)d_out;

    k1_kernel<<<NB + 1 + B_BODY + B_FACE, 256, 0, stream>>>(p);
    k2_kernel<<<NN/4, 256, 0, stream>>>(p);
    scat_kernel<<<NE/8 + NE/16, 256, 0, stream>>>(p);
}

// Round 5
// 193.481 us; speedup vs baseline: 1.3278x; 1.0220x over previous
//
#include <hip/hip_runtime.h>

#define NN 8192     // nodes
#define NB 32       // graphs
#define NG 256      // nodes per graph
#define NE 65536    // edges per graph type
#define DK 512
#define HC 32
#define DB 2048     // body visual dim
#define DF 512      // face visual dim

#define BODY_DW (NN*DB/4)            // 4194304 dwords of int8x4 (body)
#define FACE_DW (NN*DF/4)            // 1048576 dwords of int8x4 (face)
#define B_BODY (BODY_DW/2048)        // 2048 pack blocks (8 KB window = 4 body rows)
#define B_FACE (FACE_DW/2048)        // 512 pack blocks (8 KB window = 16 face rows)
#define QSCALE 16.0f                 // int8 quant scale; 1/S^2 folded into sb/sf

#define SB_BODY (NE/16)              // 4096 scat body blocks: 4 edges/wave, 4 waves
#define SB_FACE (NE/32)              // 2048 scat face blocks: 8 edges/wave (half-wave/edge), 4 waves

typedef float v4f __attribute__((ext_vector_type(4)));

#if __has_builtin(__builtin_amdgcn_sdot4)
#define HW_SDOT 1
#else
#define HW_SDOT 0
#endif

__device__ __forceinline__ unsigned pack4_i8(float4 v) {
    int i0 = (int)rintf(fmaxf(fminf(v.x * QSCALE, 127.f), -127.f));
    int i1 = (int)rintf(fmaxf(fminf(v.y * QSCALE, 127.f), -127.f));
    int i2 = (int)rintf(fmaxf(fminf(v.z * QSCALE, 127.f), -127.f));
    int i3 = (int)rintf(fmaxf(fminf(v.w * QSCALE, 127.f), -127.f));
    return (unsigned)(i0 & 255) | ((unsigned)(i1 & 255) << 8)
         | ((unsigned)(i2 & 255) << 16) | ((unsigned)(i3 & 255) << 24);
}
__device__ __forceinline__ int sdot4(int a, int b, int c) {
#if HW_SDOT
    return __builtin_amdgcn_sdot4(a, b, c, false);
#else
    c += (int)(signed char)(a)       * (int)(signed char)(b);
    c += (int)(signed char)(a >> 8)  * (int)(signed char)(b >> 8);
    c += (int)(signed char)(a >> 16) * (int)(signed char)(b >> 16);
    c += (int)(signed char)(a >> 24) * (int)(signed char)(b >> 24);
    return c;
#endif
}
__device__ __forceinline__ int dot16(int4 a, int4 b, int c) {
    c = sdot4(a.x, b.x, c);
    c = sdot4(a.y, b.y, c);
    c = sdot4(a.z, b.z, c);
    c = sdot4(a.w, b.w, c);
    return c;
}
__device__ __forceinline__ float d4(float4 v) {
    return v.x*v.x + v.y*v.y + v.z*v.z + v.w*v.w;
}
__device__ __forceinline__ v4f prelu4(v4f nd, float alpha) {
    v4f r;
    r.x = (nd.x >= 0.f) ? nd.x : alpha*nd.x;
    r.y = (nd.y >= 0.f) ? nd.y : alpha*nd.y;
    r.z = (nd.z >= 0.f) ? nd.z : alpha*nd.z;
    r.w = (nd.w >= 0.f) ? nd.w : alpha*nd.w;
    return r;
}

struct Params {
    const float *vb, *vf, *x, *Wq, *Wk, *Wv, *ln_g, *ln_b, *prelu_a;
    const float *mlp_W, *mlp_b, *np_W, *np_b, *body_W, *body_b, *face_W, *face_b;
    const float *pb_W, *pb_b, *pf_W, *pf_b;
    const int *eib, *eif;
    unsigned *vnb, *vnf;          // int8x4 tables
    float *invb, *invf;
    float *a_ws, *sb, *sf, *fused;
    // fused[64]=cb (body_b.pb_W), [65]=cf, [66..70]=s0,s1,q00,q01,q11 (Wv col stats)
    float *mvec;                  // [0,512)=mlp_W@np_W, [512,1024)=mlp_W@fb, [1024,1536)=mlp_W@ff,
                                  // [1536..1538]=mlp_b.{np,fb,ff}
    float *out;
};

// ===== K1: attention (first) + precompute tail + int8 pack with fused fp32 invnorm =====
__global__ __launch_bounds__(256) void k1_kernel(Params p) {
    __shared__ float2 xs[NG];
    __shared__ float pm[4][4];
    __shared__ float sm4[4];
    __shared__ float rss[16];
    __shared__ float wred[4][8];
    __shared__ float fs_np[HC], fs_fb[HC], fs_ff[HC];
    const int bid = blockIdx.x, tid = threadIdx.x;
    const int lane = tid & 63, wave = tid >> 6;

    if (bid < NB) {
        const int gg = bid;
        xs[tid] = ((const float2*)p.x)[gg*NG + tid];
        const int d = tid * 2;
        float q0a = p.Wq[d],    q0b = p.Wq[d+1];
        float q1a = p.Wq[DK+d], q1b = p.Wq[DK+d+1];
        float k0a = p.Wk[d],    k0b = p.Wk[d+1];
        float k1a = p.Wk[DK+d], k1b = p.Wk[DK+d+1];
        float m00 = q0a*k0a + q0b*k0b;
        float m01 = q0a*k1a + q0b*k1b;
        float m10 = q1a*k0a + q1b*k0b;
        float m11 = q1a*k1a + q1b*k1b;
        #pragma unroll
        for (int off = 32; off > 0; off >>= 1) {
            m00 += __shfl_down(m00,off); m01 += __shfl_down(m01,off);
            m10 += __shfl_down(m10,off); m11 += __shfl_down(m11,off);
        }
        if (lane == 0) { pm[wave][0]=m00; pm[wave][1]=m01; pm[wave][2]=m10; pm[wave][3]=m11; }
        __syncthreads();
        if (tid < 4) sm4[tid] = pm[0][tid] + pm[1][tid] + pm[2][tid] + pm[3][tid];
        __syncthreads();
        const float scale = 0.04419417382415922f;  // 1/sqrt(512)
        const float2 xi = xs[tid];
        const float u0 = (xi.x*sm4[0] + xi.y*sm4[2]) * scale;
        const float u1 = (xi.x*sm4[1] + xi.y*sm4[3]) * scale;
        float m = -1e30f;
        for (int j = 0; j < NG; j++) m = fmaxf(m, u0*xs[j].x + u1*xs[j].y);
        float S = 0.f, a0 = 0.f, a1 = 0.f;
        for (int j = 0; j < NG; j++) {
            float2 xj = xs[j];
            float pr = __expf(u0*xj.x + u1*xj.y - m);
            S += pr; a0 += pr*xj.x; a1 += pr*xj.y;
        }
        const float invS = 1.f / S;
        ((float2*)p.a_ws)[gg*NG + tid] = make_float2(a0*invS, a1*invS);
        return;
    }
    if (bid == NB) {
        {
            const int d = tid * 2;
            float u0 = p.Wv[d], u1 = p.Wv[d+1];
            float w0 = p.Wv[DK+d], w1 = p.Wv[DK+d+1];
            float s0 = u0 + u1, s1 = w0 + w1;
            float q00 = u0*u0 + u1*u1, q01 = u0*w0 + u1*w1, q11 = w0*w0 + w1*w1;
            #pragma unroll
            for (int off = 1; off < 64; off <<= 1) {
                s0 += __shfl_xor(s0,off); s1 += __shfl_xor(s1,off);
                q00 += __shfl_xor(q00,off); q01 += __shfl_xor(q01,off); q11 += __shfl_xor(q11,off);
            }
            if (lane == 0) {
                wred[wave][0]=s0; wred[wave][1]=s1; wred[wave][2]=q00; wred[wave][3]=q01; wred[wave][4]=q11;
            }
        }
        if (tid < HC) {
            float sB = 0.f, sF = 0.f;
            #pragma unroll 8
            for (int c = 0; c < HC; c++) {
                sB += p.body_W[tid*HC + c] * p.pb_W[c];
                sF += p.face_W[tid*HC + c] * p.pf_W[c];
            }
            fs_fb[tid] = sB; fs_ff[tid] = sF;
            fs_np[tid] = p.np_W[tid];
        } else if (tid == HC) {
            float s = 0.f;
            for (int c = 0; c < HC; c++) s += p.body_b[c] * p.pb_W[c];
            p.fused[64] = s;
        } else if (tid == HC + 1) {
            float s = 0.f;
            for (int c = 0; c < HC; c++) s += p.face_b[c] * p.pf_W[c];
            p.fused[65] = s;
        }
        __syncthreads();
        if (tid < 5) p.fused[66+tid] = wred[0][tid]+wred[1][tid]+wred[2][tid]+wred[3][tid];
        #pragma unroll
        for (int rr = tid; rr < DK; rr += 256) {
            const float* row = p.mlp_W + rr*HC;
            float dnp = 0.f, db = 0.f, df = 0.f;
            #pragma unroll 8
            for (int c = 0; c < HC; c++) {
                float w = row[c];
                dnp += w * fs_np[c]; db += w * fs_fb[c]; df += w * fs_ff[c];
            }
            p.mvec[rr] = dnp; p.mvec[DK + rr] = db; p.mvec[2*DK + rr] = df;
        }
        if (tid < 3) {
            const float* fv = (tid == 0) ? fs_np : (tid == 1) ? fs_fb : fs_ff;
            float s = 0.f;
            for (int c = 0; c < HC; c++) s += p.mlp_b[c] * fv[c];
            p.mvec[3*DK + tid] = s;
        }
        return;
    }
    {
        const int pb = bid - (NB + 1);
        const bool body = pb < B_BODY;
        const float4* __restrict__ src = body ? (const float4*)p.vb : (const float4*)p.vf;
        unsigned* __restrict__ dst = body ? p.vnb : p.vnf;
        const int base = (body ? pb : pb - B_BODY) * 2048 + tid;
        if (tid < 16) rss[tid] = 0.f;
        __syncthreads();
        float4 v0 = src[base];
        float4 v1 = src[base + 256];
        float4 v2 = src[base + 512];
        float4 v3 = src[base + 768];
        float4 v4 = src[base + 1024];
        float4 v5 = src[base + 1280];
        float4 v6 = src[base + 1536];
        float4 v7 = src[base + 1792];
        __builtin_amdgcn_sched_barrier(0);   // all 8 loads issue before any consumer
        dst[base]        = pack4_i8(v0);
        dst[base + 256]  = pack4_i8(v1);
        dst[base + 512]  = pack4_i8(v2);
        dst[base + 768]  = pack4_i8(v3);
        dst[base + 1024] = pack4_i8(v4);
        dst[base + 1280] = pack4_i8(v5);
        dst[base + 1536] = pack4_i8(v6);
        dst[base + 1792] = pack4_i8(v7);
        if (body) {
            float sq[4];
            sq[0] = d4(v0) + d4(v1);
            sq[1] = d4(v2) + d4(v3);
            sq[2] = d4(v4) + d4(v5);
            sq[3] = d4(v6) + d4(v7);
            #pragma unroll
            for (int r = 0; r < 4; r++) {
                float ss = sq[r];
                #pragma unroll
                for (int off = 32; off > 0; off >>= 1) ss += __shfl_xor(ss, off);
                if (lane == 0) atomicAdd(&rss[r], ss);
            }
            __syncthreads();
            if (tid < 4) p.invb[pb*4 + tid] = rsqrtf(rss[tid] + 1e-8f);
        } else {
            float sq[8] = {d4(v0), d4(v1), d4(v2), d4(v3), d4(v4), d4(v5), d4(v6), d4(v7)};
            #pragma unroll
            for (int j = 0; j < 8; j++) {
                float ss = sq[j];
                #pragma unroll
                for (int off = 32; off > 0; off >>= 1) ss += __shfl_xor(ss, off);
                if (lane == 0) atomicAdd(&rss[(wave >> 1) + 2*j], ss);
            }
            __syncthreads();
            if (tid < 16) p.invf[(pb - B_BODY)*16 + tid] = rsqrtf(rss[tid] + 1e-8f);
        }
    }
}

// ===== K2: node pipeline via collapsed projections (1 node / wave, no LDS) =====
__global__ __launch_bounds__(256) void k2_kernel(Params p) {
    const int tid = threadIdx.x;
    const int wave = tid >> 6, lane = tid & 63;
    const int node = blockIdx.x * 4 + wave;

    const float a0 = p.a_ws[node*2], a1 = p.a_ws[node*2+1];
    const float s0 = p.fused[66], s1 = p.fused[67];
    const float q00 = p.fused[68], q01 = p.fused[69], q11 = p.fused[70];
    const float mean = (a0*s0 + a1*s1) * (1.f/DK);
    const float msq  = (a0*a0*q00 + 2.f*a0*a1*q01 + a1*a1*q11) * (1.f/DK);
    const float inv  = rsqrtf(msq - mean*mean + 1e-5f);
    const float alpha = p.prelu_a[0];

    const v4f* wv0 = (const v4f*)p.Wv;
    const v4f* wv1 = (const v4f*)(p.Wv + DK);
    const v4f* g4 = (const v4f*)p.ln_g;
    const v4f* b4 = (const v4f*)p.ln_b;
    const v4f* mnp = (const v4f*)p.mvec;
    const v4f* mb  = (const v4f*)(p.mvec + DK);
    const v4f* mf  = (const v4f*)(p.mvec + 2*DK);

    const int c4 = lane * 2;
    v4f t0 = prelu4((a0*wv0[c4]   + a1*wv1[c4]   - mean) * inv * g4[c4]   + b4[c4],   alpha);
    v4f t1 = prelu4((a0*wv0[c4+1] + a1*wv1[c4+1] - mean) * inv * g4[c4+1] + b4[c4+1], alpha);

    v4f q0 = t0*mnp[c4] + t1*mnp[c4+1];
    v4f q1 = t0*mb[c4]  + t1*mb[c4+1];
    v4f q2 = t0*mf[c4]  + t1*mf[c4+1];
    float d0 = (q0.x+q0.y) + (q0.z+q0.w);
    float d1 = (q1.x+q1.y) + (q1.z+q1.w);
    float d2 = (q2.x+q2.y) + (q2.z+q2.w);
    #pragma unroll
    for (int off = 1; off < 64; off <<= 1) {
        d0 += __shfl_xor(d0, off);
        d1 += __shfl_xor(d1, off);
        d2 += __shfl_xor(d2, off);
    }
    if (lane == 0) {
        const float qinv2 = 1.0f / (QSCALE * QSCALE);
        p.out[node] = d0 + p.mvec[3*DK] + p.np_b[0] + p.pb_b[0] + p.pf_b[0];
        p.sb[node] = (d1 + p.mvec[3*DK+1] + p.fused[64]) * qinv2;
        p.sf[node] = (d2 + p.mvec[3*DK+2] + p.fused[65]) * qinv2;
    }
}

// ===== K3: edge-direct int8 cosine scatter, deep-ILP =====
// blocks [0, SB_BODY)             : body, 4 edges/wave (16x int4 in flight)
// blocks [SB_BODY, +SB_FACE)      : face, 8 edges/wave, half-wave per edge (8x int4 in flight)
__global__ __launch_bounds__(256) void scat_kernel(Params p) {
    const int wave = threadIdx.x >> 6, lane = threadIdx.x & 63;
    if (blockIdx.x < SB_BODY) {
        const int e0 = (blockIdx.x * 4 + wave) * 4;
        const int4 si = *(const int4*)(p.eib + e0);        // 4 src indices (wave-uniform)
        const int4 di = *(const int4*)(p.eib + NE + e0);   // 4 dst indices
        const int4* S0 = (const int4*)(p.vnb + (size_t)si.x * (DB/4));
        const int4* D0 = (const int4*)(p.vnb + (size_t)di.x * (DB/4));
        const int4* S1 = (const int4*)(p.vnb + (size_t)si.y * (DB/4));
        const int4* D1 = (const int4*)(p.vnb + (size_t)di.y * (DB/4));
        const int4* S2 = (const int4*)(p.vnb + (size_t)si.z * (DB/4));
        const int4* D2 = (const int4*)(p.vnb + (size_t)di.z * (DB/4));
        const int4* S3 = (const int4*)(p.vnb + (size_t)si.w * (DB/4));
        const int4* D3 = (const int4*)(p.vnb + (size_t)di.w * (DB/4));
        int4 a00 = S0[lane], a01 = S0[lane + 64];
        int4 b00 = D0[lane], b01 = D0[lane + 64];
        int4 a10 = S1[lane], a11 = S1[lane + 64];
        int4 b10 = D1[lane], b11 = D1[lane + 64];
        int4 a20 = S2[lane], a21 = S2[lane + 64];
        int4 b20 = D2[lane], b21 = D2[lane + 64];
        int4 a30 = S3[lane], a31 = S3[lane + 64];
        int4 b30 = D3[lane], b31 = D3[lane + 64];
        __builtin_amdgcn_sched_barrier(0);   // all 16 row loads in flight before compute
        int x0 = dot16(a01, b01, dot16(a00, b00, 0));
        int x1 = dot16(a11, b11, dot16(a10, b10, 0));
        int x2 = dot16(a21, b21, dot16(a20, b20, 0));
        int x3 = dot16(a31, b31, dot16(a30, b30, 0));
        #pragma unroll
        for (int off = 1; off < 64; off <<= 1) {
            x0 += __shfl_xor(x0, off);
            x1 += __shfl_xor(x1, off);
            x2 += __shfl_xor(x2, off);
            x3 += __shfl_xor(x3, off);
        }
        if (lane == 0) {
            atomicAdd(&p.out[di.x], (float)x0 * p.invb[si.x] * p.invb[di.x] * p.sb[si.x]);
            atomicAdd(&p.out[di.y], (float)x1 * p.invb[si.y] * p.invb[di.y] * p.sb[si.y]);
            atomicAdd(&p.out[di.z], (float)x2 * p.invb[si.z] * p.invb[di.z] * p.sb[si.z]);
            atomicAdd(&p.out[di.w], (float)x3 * p.invb[si.w] * p.invb[di.w] * p.sb[si.w]);
        }
    } else {
        // face: half-wave per edge; slot t handles edges e0+2t (lanes 0-31) and e0+2t+1 (lanes 32-63)
        const int e0 = ((blockIdx.x - SB_BODY) * 4 + wave) * 8;
        const int h = lane >> 5, l32 = lane & 31;
        const int eA = e0 + h,     eB = e0 + 2 + h;
        const int eC = e0 + 4 + h, eD = e0 + 6 + h;
        const int sA = p.eif[eA], dA = p.eif[NE + eA];
        const int sB = p.eif[eB], dB = p.eif[NE + eB];
        const int sC = p.eif[eC], dC = p.eif[NE + eC];
        const int sD = p.eif[eD], dD = p.eif[NE + eD];
        const int4* SA = (const int4*)(p.vnf + (size_t)sA * (DF/4));
        const int4* DA = (const int4*)(p.vnf + (size_t)dA * (DF/4));
        const int4* SB4 = (const int4*)(p.vnf + (size_t)sB * (DF/4));
        const int4* DB4 = (const int4*)(p.vnf + (size_t)dB * (DF/4));
        const int4* SC = (const int4*)(p.vnf + (size_t)sC * (DF/4));
        const int4* DC = (const int4*)(p.vnf + (size_t)dC * (DF/4));
        const int4* SD = (const int4*)(p.vnf + (size_t)sD * (DF/4));
        const int4* DD = (const int4*)(p.vnf + (size_t)dD * (DF/4));
        int4 aA = SA[l32],  bA = DA[l32];
        int4 aB = SB4[l32], bB = DB4[l32];
        int4 aC = SC[l32],  bC = DC[l32];
        int4 aD = SD[l32],  bD = DD[l32];
        __builtin_amdgcn_sched_barrier(0);   // all 8 row loads in flight before compute
        int x0 = dot16(aA, bA, 0);
        int x1 = dot16(aB, bB, 0);
        int x2 = dot16(aC, bC, 0);
        int x3 = dot16(aD, bD, 0);
        #pragma unroll
        for (int off = 1; off < 32; off <<= 1) {
            x0 += __shfl_xor(x0, off);
            x1 += __shfl_xor(x1, off);
            x2 += __shfl_xor(x2, off);
            x3 += __shfl_xor(x3, off);
        }
        if (l32 == 0) {
            atomicAdd(&p.out[dA], (float)x0 * p.invf[sA] * p.invf[dA] * p.sf[sA]);
            atomicAdd(&p.out[dB], (float)x1 * p.invf[sB] * p.invf[dB] * p.sf[sB]);
            atomicAdd(&p.out[dC], (float)x2 * p.invf[sC] * p.invf[dC] * p.sf[sC]);
            atomicAdd(&p.out[dD], (float)x3 * p.invf[sD] * p.invf[dD] * p.sf[sD]);
        }
    }
}

extern "C" void kernel_launch(void* const* d_in, const int* in_sizes, int n_in,
                              void* d_out, int out_size, void* d_ws, size_t ws_size,
                              hipStream_t stream) {
    char* ws = (char*)d_ws;
    size_t off = 0;
    auto alloc = [&](size_t bytes) { void* pp = ws + off; off += (bytes + 15) & ~size_t(15); return pp; };

    Params p;
    p.vb      = (const float*)d_in[1];
    p.vf      = (const float*)d_in[2];
    p.x       = (const float*)d_in[0];
    p.Wq      = (const float*)d_in[3];
    p.Wk      = (const float*)d_in[4];
    p.Wv      = (const float*)d_in[5];
    p.ln_g    = (const float*)d_in[6];
    p.ln_b    = (const float*)d_in[7];
    p.prelu_a = (const float*)d_in[8];
    p.mlp_W   = (const float*)d_in[9];
    p.mlp_b   = (const float*)d_in[10];
    p.np_W    = (const float*)d_in[11];
    p.np_b    = (const float*)d_in[12];
    p.body_W  = (const float*)d_in[13];
    p.body_b  = (const float*)d_in[14];
    p.face_W  = (const float*)d_in[15];
    p.face_b  = (const float*)d_in[16];
    p.pb_W    = (const float*)d_in[17];
    p.pb_b    = (const float*)d_in[18];
    p.pf_W    = (const float*)d_in[19];
    p.pf_b    = (const float*)d_in[20];
    p.eib     = (const int*)d_in[21];
    p.eif     = (const int*)d_in[22];
    p.vnb     = (unsigned*)alloc((size_t)BODY_DW*4);     // 16 MB int8
    p.vnf     = (unsigned*)alloc((size_t)FACE_DW*4);     //  4 MB int8
    p.invb    = (float*)alloc((size_t)NN*4);
    p.invf    = (float*)alloc((size_t)NN*4);
    p.a_ws    = (float*)alloc((size_t)NN*2*4);
    p.sb      = (float*)alloc((size_t)NN*4);
    p.sf      = (float*)alloc((size_t)NN*4);
    p.fused   = (float*)alloc((size_t)72*4);
    p.mvec    = (float*)alloc((size_t)1544*4);
    p.out     = (float*)d_out;

    k1_kernel<<<NB + 1 + B_BODY + B_FACE, 256, 0, stream>>>(p);
    k2_kernel<<<NN/4, 256, 0, stream>>>(p);
    scat_kernel<<<SB_BODY + SB_FACE, 256, 0, stream>>>(p);
}